// Round 2
// baseline (4001.195 us; speedup 1.0000x reference)
//
#include <hip/hip_runtime.h>

#define T_STEPS 31
#define CIN     64
#define COUT    512
#define WSLEN   512
#define KSZ     32
#define CSTRIDE 16
#define KRED    2048                 // CIN*KSZ
#define NBATCH  1024
#define BCHUNK  512                  // batch rows per pass (seq buffer reuse)
#define MCHUNK  (BCHUNK * T_STEPS)   // 15872 rows per pass

__device__ __forceinline__ double clip01d(double v) { return fmin(fmax(v, 0.0), 1.0); }

// ---------------------------------------------------------------------------
// Prep: transpose conv_w [co][ci][k] -> wT [r=ci*32+k][co]   (f32, exact)
//       transpose fc1_w  [co][c]     -> fc1wT [c][co]        (f32, exact)
// ---------------------------------------------------------------------------
__global__ __launch_bounds__(256) void prep_kernel(
    const float* __restrict__ conv_w, const float* __restrict__ fc1_w,
    float* __restrict__ wT, float* __restrict__ fc1wT)
{
    int idx = blockIdx.x * 256 + threadIdx.x;
    int co = idx & 511;
    int r  = idx >> 9;
    if (idx < KRED * COUT)  wT[idx]    = conv_w[co * KRED + r];
    if (idx < COUT * COUT)  fc1wT[idx] = fc1_w[co * COUT + r];
}

// ---------------------------------------------------------------------------
// Conv1d + BN, f64 accumulation. Implicit im2col GEMM:
// M = MCHUNK rows (b,t), N = 512 (co), K = 2048 (ci,k). BM=BN=64, BK=16.
// 256 threads, 4x4 f64 micro-tile. seq[m_local][co] double output.
// ---------------------------------------------------------------------------
__global__ __launch_bounds__(256) void conv_bn_f64_kernel(
    const float* __restrict__ x, const float* __restrict__ wT,
    const float* __restrict__ conv_b,
    const float* __restrict__ bn_gamma, const float* __restrict__ bn_beta,
    const float* __restrict__ bn_mean,  const float* __restrict__ bn_var,
    double* __restrict__ seq, int b_base)
{
    __shared__ double As[16][64];   // k-major
    __shared__ double Bs[16][64];

    const int tid = threadIdx.x;
    const int nMB = MCHUNK / 64;           // 248
    const int bm = blockIdx.x % nMB;
    const int bn = blockIdx.x / nMB;
    const int m0 = bm * 64, n0 = bn * 64;

    // A-load: row miA, k-quad kqA (kqA*4 .. kqA*4+3 within the 16-wide K tile)
    const int miA = tid & 63;
    const int kqA = tid >> 6;              // 0..3
    const int mA  = m0 + miA;
    const int bA  = b_base + mA / T_STEPS;
    const int tA  = mA % T_STEPS;
    const float* xp = x + (size_t)bA * CIN * WSLEN + tA * CSTRIDE;

    // B-load: row rB (0..15), col quad nqB
    const int rB  = tid >> 4;
    const int nqB = tid & 15;

    const int tx = tid & 15, ty = tid >> 4;
    double acc[4][4] = {};

    for (int it = 0; it < KRED / 16; ++it) {
        const int kt = it * 16;
        const int ci = kt >> 5;            // 32 k per input channel
        const int ks = kt & 31;            // 0 or 16
        float4 a = *(const float4*)(xp + ci * WSLEN + ks + kqA * 4);
        float4 b = *(const float4*)(wT + (size_t)(kt + rB) * COUT + n0 + nqB * 4);
        __syncthreads();
        As[kqA * 4 + 0][miA] = (double)a.x;
        As[kqA * 4 + 1][miA] = (double)a.y;
        As[kqA * 4 + 2][miA] = (double)a.z;
        As[kqA * 4 + 3][miA] = (double)a.w;
        Bs[rB][nqB * 4 + 0] = (double)b.x;
        Bs[rB][nqB * 4 + 1] = (double)b.y;
        Bs[rB][nqB * 4 + 2] = (double)b.z;
        Bs[rB][nqB * 4 + 3] = (double)b.w;
        __syncthreads();
        #pragma unroll
        for (int kk = 0; kk < 16; ++kk) {
            double av[4], bv[4];
            *(double2*)&av[0] = *(const double2*)&As[kk][ty * 4 + 0];
            *(double2*)&av[2] = *(const double2*)&As[kk][ty * 4 + 2];
            *(double2*)&bv[0] = *(const double2*)&Bs[kk][tx * 4 + 0];
            *(double2*)&bv[2] = *(const double2*)&Bs[kk][tx * 4 + 2];
            #pragma unroll
            for (int i = 0; i < 4; ++i)
                #pragma unroll
                for (int j = 0; j < 4; ++j)
                    acc[i][j] = fma(av[i], bv[j], acc[i][j]);
        }
    }

    // Epilogue: conv bias + BN (eval) in f64, store double
    const int nb = n0 + tx * 4;
    #pragma unroll
    for (int j = 0; j < 4; ++j) {
        double g  = (double)bn_gamma[nb + j];
        double be = (double)bn_beta[nb + j];
        double mn = (double)bn_mean[nb + j];
        double vr = (double)bn_var[nb + j];
        double cb = (double)conv_b[nb + j];
        double inv = 1.0 / sqrt(vr + 1e-5);
        #pragma unroll
        for (int i = 0; i < 4; ++i) {
            int m = m0 + ty * 4 + i;
            seq[(size_t)m * COUT + nb + j] = g * (acc[i][j] + cb - mn) * inv + be;
        }
    }
}

// ---------------------------------------------------------------------------
// SNN scan, f64 state. 4 batch rows per block, 256 threads (co = tid, tid+256).
// Encoder spikes -> 64-bit ballots in LDS; fc1 = wave-uniform sparse loop over
// set bits, f64 accumulation of f32 weights (exact). fc2 via shfl + LDS reduce.
// out layout: om[2048] | spk_rec[31*2048] | mem_rec[31*2048]   (f32)
// ---------------------------------------------------------------------------
__global__ __launch_bounds__(256) void snn_scan_f64_kernel(
    const double* __restrict__ seq, const float* __restrict__ fc1wT,
    const float* __restrict__ fc1_b, const float* __restrict__ fc2_w,
    const float* __restrict__ fc2_b, const float* __restrict__ beta_enc,
    const float* __restrict__ beta_hid, const float* __restrict__ beta_out,
    float* __restrict__ out, int b_base)
{
    __shared__ unsigned long long masks[4][8];
    __shared__ double red[4][2][4];

    const int tid  = threadIdx.x;
    const int lane = tid & 63;
    const int wave = tid >> 6;
    const int rbl  = blockIdx.x * 4;       // local batch row base within chunk
    const int c0 = tid, c1 = tid + 256;

    const double be0 = clip01d((double)beta_enc[c0]), be1 = clip01d((double)beta_enc[c1]);
    const double bh0 = clip01d((double)beta_hid[c0]), bh1 = clip01d((double)beta_hid[c1]);
    const double f1b0 = (double)fc1_b[c0], f1b1 = (double)fc1_b[c1];
    const double w2_00 = (double)fc2_w[c0],        w2_01 = (double)fc2_w[COUT + c0];
    const double w2_10 = (double)fc2_w[c1],        w2_11 = (double)fc2_w[COUT + c1];
    double bo = 0.0, f2b = 0.0, om = 0.0;
    if (tid < 8) { bo = clip01d((double)beta_out[tid & 1]); f2b = (double)fc2_b[tid & 1]; }

    double em0[4] = {}, em1[4] = {}, hm0[4] = {}, hm1[4] = {};

    for (int t = 0; t < T_STEPS; ++t) {
        // ---- encoder leaky + spike ballots ----
        #pragma unroll
        for (int r = 0; r < 4; ++r) {
            const double* sp = seq + ((size_t)(rbl + r) * T_STEPS + t) * COUT;
            double i0 = sp[c0], i1 = sp[c1];
            double e0 = em0[r], e1 = em1[r];
            e0 = be0 * e0 + i0 - ((e0 > 1.0) ? 1.0 : 0.0);
            e1 = be1 * e1 + i1 - ((e1 > 1.0) ? 1.0 : 0.0);
            em0[r] = e0; em1[r] = e1;
            unsigned long long ball0 = __ballot(e0 > 1.0);
            unsigned long long ball1 = __ballot(e1 > 1.0);
            if (lane == 0) { masks[r][wave] = ball0; masks[r][4 + wave] = ball1; }
        }
        __syncthreads();

        // ---- fc1: sparse, wave-uniform iteration over active input channels ----
        double a0[4] = {}, a1[4] = {};
        #pragma unroll
        for (int r = 0; r < 4; ++r) {
            #pragma unroll 1
            for (int ch = 0; ch < 8; ++ch) {
                unsigned long long m = masks[r][ch];
                const float* wr = fc1wT + (size_t)(ch * 64) * COUT;
                while (m) {
                    int cb = __builtin_ctzll(m);
                    m &= m - 1;
                    a0[r] += (double)wr[(size_t)cb * COUT + c0];
                    a1[r] += (double)wr[(size_t)cb * COUT + c1];
                }
            }
        }

        // ---- hidden leaky + fc2 partials ----
        double p[4][2];
        #pragma unroll
        for (int r = 0; r < 4; ++r) {
            double cur0 = a0[r] + f1b0;
            double cur1 = a1[r] + f1b1;
            double h0 = hm0[r], h1 = hm1[r];
            h0 = bh0 * h0 + cur0 - ((h0 > 1.0) ? 1.0 : 0.0);
            h1 = bh1 * h1 + cur1 - ((h1 > 1.0) ? 1.0 : 0.0);
            hm0[r] = h0; hm1[r] = h1;
            double sh0 = (h0 > 1.0) ? 1.0 : 0.0;
            double sh1 = (h1 > 1.0) ? 1.0 : 0.0;
            p[r][0] = sh0 * w2_00 + sh1 * w2_10;
            p[r][1] = sh0 * w2_01 + sh1 * w2_11;
        }
        #pragma unroll
        for (int off = 32; off > 0; off >>= 1) {
            #pragma unroll
            for (int r = 0; r < 4; ++r) {
                p[r][0] += __shfl_down(p[r][0], off);
                p[r][1] += __shfl_down(p[r][1], off);
            }
        }
        if (lane == 0) {
            #pragma unroll
            for (int r = 0; r < 4; ++r) { red[r][0][wave] = p[r][0]; red[r][1][wave] = p[r][1]; }
        }
        __syncthreads();

        // ---- output layer (threads 0..7: r = tid>>1, j = tid&1) ----
        if (tid < 8) {
            int r = tid >> 1, j = tid & 1;
            double cur2 = red[r][j][0] + red[r][j][1] + red[r][j][2] + red[r][j][3] + f2b;
            double o = bo * om + cur2 - ((om > 1.0) ? 1.0 : 0.0);
            om = o;
            float so = (o > 1.0) ? 1.0f : 0.0f;
            int bidx = (b_base + rbl + r) * 2 + j;
            out[2048 + t * 2048 + bidx] = so;               // spk_rec
            out[2048 + 63488 + t * 2048 + bidx] = (float)o; // mem_rec
            if (t == T_STEPS - 1) out[bidx] = (float)o;     // final om
        }
    }
}

// ---------------------------------------------------------------------------
extern "C" void kernel_launch(void* const* d_in, const int* in_sizes, int n_in,
                              void* d_out, int out_size, void* d_ws, size_t ws_size,
                              hipStream_t stream)
{
    const float* x        = (const float*)d_in[0];
    const float* conv_w   = (const float*)d_in[1];
    const float* conv_b   = (const float*)d_in[2];
    const float* bn_gamma = (const float*)d_in[3];
    const float* bn_beta  = (const float*)d_in[4];
    const float* bn_mean  = (const float*)d_in[5];
    const float* bn_var   = (const float*)d_in[6];
    const float* fc1_w    = (const float*)d_in[7];
    const float* fc1_b    = (const float*)d_in[8];
    const float* fc2_w    = (const float*)d_in[9];
    const float* fc2_b    = (const float*)d_in[10];
    const float* beta_enc = (const float*)d_in[11];
    const float* beta_hid = (const float*)d_in[12];
    const float* beta_out = (const float*)d_in[13];
    float* out = (float*)d_out;

    float*  wT    = (float*)d_ws;                       // [2048][512] f32, 4 MB
    float*  fc1wT = wT + (size_t)KRED * COUT;           // [512][512]  f32, 1 MB
    double* seq   = (double*)(fc1wT + (size_t)COUT * COUT); // [15872][512] f64, 65 MB (offset 5242880, 8B-aligned)

    prep_kernel<<<4096, 256, 0, stream>>>(conv_w, fc1_w, wT, fc1wT);

    for (int chunk = 0; chunk < 2; ++chunk) {
        int b_base = chunk * BCHUNK;
        conv_bn_f64_kernel<<<(MCHUNK / 64) * (COUT / 64), 256, 0, stream>>>(
            x, wT, conv_b, bn_gamma, bn_beta, bn_mean, bn_var, seq, b_base);
        snn_scan_f64_kernel<<<BCHUNK / 4, 256, 0, stream>>>(
            seq, fc1wT, fc1_b, fc2_w, fc2_b, beta_enc, beta_hid, beta_out, out, b_base);
    }
}

// Round 3
// 1980.626 us; speedup vs baseline: 2.0202x; 2.0202x over previous
//
#include <hip/hip_runtime.h>

#define T_STEPS 31
#define CIN     64
#define COUT    512
#define WSLEN   512
#define KSZ     32
#define CSTRIDE 16
#define KRED    2048                 // CIN*KSZ
#define NBATCH  1024
#define BCHUNK  512                  // batch rows per pass (seq buffer reuse)
#define MCHUNK  (BCHUNK * T_STEPS)   // 15872 rows per pass

__device__ __forceinline__ double clip01d(double v) { return fmin(fmax(v, 0.0), 1.0); }

// ---------------------------------------------------------------------------
// Prep: transpose conv_w [co][ci][k] -> wT [r=ci*32+k][co]   (f32, exact)
//       transpose fc1_w  [co][c]     -> fc1wT [c][co]        (f32, exact)
// ---------------------------------------------------------------------------
__global__ __launch_bounds__(256) void prep_kernel(
    const float* __restrict__ conv_w, const float* __restrict__ fc1_w,
    float* __restrict__ wT, float* __restrict__ fc1wT)
{
    int idx = blockIdx.x * 256 + threadIdx.x;
    int co = idx & 511;
    int r  = idx >> 9;
    if (idx < KRED * COUT)  wT[idx]    = conv_w[co * KRED + r];
    if (idx < COUT * COUT)  fc1wT[idx] = fc1_w[co * COUT + r];
}

// ---------------------------------------------------------------------------
// Conv1d + BN, f64 accumulation (at f64 vector roofline ~850us/chunk).
// M = MCHUNK rows (b,t), N = 512 (co), K = 2048. BM=BN=64, BK=16.
// ---------------------------------------------------------------------------
__global__ __launch_bounds__(256) void conv_bn_f64_kernel(
    const float* __restrict__ x, const float* __restrict__ wT,
    const float* __restrict__ conv_b,
    const float* __restrict__ bn_gamma, const float* __restrict__ bn_beta,
    const float* __restrict__ bn_mean,  const float* __restrict__ bn_var,
    double* __restrict__ seq, int b_base)
{
    __shared__ double As[16][64];   // k-major
    __shared__ double Bs[16][64];

    const int tid = threadIdx.x;
    const int nMB = MCHUNK / 64;           // 248
    const int bm = blockIdx.x % nMB;
    const int bn = blockIdx.x / nMB;
    const int m0 = bm * 64, n0 = bn * 64;

    const int miA = tid & 63;
    const int kqA = tid >> 6;              // 0..3
    const int mA  = m0 + miA;
    const int bA  = b_base + mA / T_STEPS;
    const int tA  = mA % T_STEPS;
    const float* xp = x + (size_t)bA * CIN * WSLEN + tA * CSTRIDE;

    const int rB  = tid >> 4;
    const int nqB = tid & 15;

    const int tx = tid & 15, ty = tid >> 4;
    double acc[4][4] = {};

    for (int it = 0; it < KRED / 16; ++it) {
        const int kt = it * 16;
        const int ci = kt >> 5;
        const int ks = kt & 31;
        float4 a = *(const float4*)(xp + ci * WSLEN + ks + kqA * 4);
        float4 b = *(const float4*)(wT + (size_t)(kt + rB) * COUT + n0 + nqB * 4);
        __syncthreads();
        As[kqA * 4 + 0][miA] = (double)a.x;
        As[kqA * 4 + 1][miA] = (double)a.y;
        As[kqA * 4 + 2][miA] = (double)a.z;
        As[kqA * 4 + 3][miA] = (double)a.w;
        Bs[rB][nqB * 4 + 0] = (double)b.x;
        Bs[rB][nqB * 4 + 1] = (double)b.y;
        Bs[rB][nqB * 4 + 2] = (double)b.z;
        Bs[rB][nqB * 4 + 3] = (double)b.w;
        __syncthreads();
        #pragma unroll
        for (int kk = 0; kk < 16; ++kk) {
            double av[4], bv[4];
            *(double2*)&av[0] = *(const double2*)&As[kk][ty * 4 + 0];
            *(double2*)&av[2] = *(const double2*)&As[kk][ty * 4 + 2];
            *(double2*)&bv[0] = *(const double2*)&Bs[kk][tx * 4 + 0];
            *(double2*)&bv[2] = *(const double2*)&Bs[kk][tx * 4 + 2];
            #pragma unroll
            for (int i = 0; i < 4; ++i)
                #pragma unroll
                for (int j = 0; j < 4; ++j)
                    acc[i][j] = fma(av[i], bv[j], acc[i][j]);
        }
    }

    const int nb = n0 + tx * 4;
    #pragma unroll
    for (int j = 0; j < 4; ++j) {
        double g  = (double)bn_gamma[nb + j];
        double be = (double)bn_beta[nb + j];
        double mn = (double)bn_mean[nb + j];
        double vr = (double)bn_var[nb + j];
        double cb = (double)conv_b[nb + j];
        double inv = 1.0 / sqrt(vr + 1e-5);
        #pragma unroll
        for (int i = 0; i < 4; ++i) {
            int m = m0 + ty * 4 + i;
            seq[(size_t)m * COUT + nb + j] = g * (acc[i][j] + cb - mn) * inv + be;
        }
    }
}

// ---------------------------------------------------------------------------
// SNN scan v3: 1 batch row per block, 512 threads (thread = output channel).
// Grid = BCHUNK blocks -> 2 blocks/CU, 16 waves/CU.
// Encoder spikes compacted to a sorted active-index list (ballot + prefix);
// fc1 = counted loop over list, unrolled x4 with 4 independent f64 partials.
// fc2 via f64 shfl reduce + LDS; out-neuron state in regs of threads 0/1.
// out layout: om[2048] | spk_rec[31*2048] | mem_rec[31*2048]   (f32)
// ---------------------------------------------------------------------------
__global__ __launch_bounds__(512, 4) void snn_scan_v3_kernel(
    const double* __restrict__ seq, const float* __restrict__ fc1wT,
    const float* __restrict__ fc1_b, const float* __restrict__ fc2_w,
    const float* __restrict__ fc2_b, const float* __restrict__ beta_enc,
    const float* __restrict__ beta_hid, const float* __restrict__ beta_out,
    float* __restrict__ out, int b_base)
{
    __shared__ int   list[COUT];
    __shared__ int   wcnt[8];
    __shared__ double red[8][2];

    const int tid  = threadIdx.x;
    const int lane = tid & 63;
    const int wave = tid >> 6;
    const int row  = blockIdx.x;            // local row within chunk
    const int brow = b_base + row;          // global batch row

    const double be  = clip01d((double)beta_enc[tid]);
    const double bh  = clip01d((double)beta_hid[tid]);
    const double f1b = (double)fc1_b[tid];
    const double w2a = (double)fc2_w[tid];
    const double w2b = (double)fc2_w[COUT + tid];

    double bo = 0.0, f2b = 0.0, om = 0.0;   // output-neuron state on threads 0/1
    if (tid < 2) { bo = clip01d((double)beta_out[tid]); f2b = (double)fc2_b[tid]; }

    double em = 0.0, hm = 0.0;
    const double* sp = seq + (size_t)row * T_STEPS * COUT + tid;

    for (int t = 0; t < T_STEPS; ++t) {
        // ---- encoder leaky + spike ----
        double inp = sp[(size_t)t * COUT];
        double e = be * em + inp - ((em > 1.0) ? 1.0 : 0.0);
        em = e;
        bool spike = (e > 1.0);

        unsigned long long mask = __ballot(spike);
        if (lane == 0) wcnt[wave] = __popcll(mask);
        __syncthreads();                    // wcnt ready; prev-step list reads done

        int base = 0, cnt = 0;
        #pragma unroll
        for (int w = 0; w < 8; ++w) {
            int v = wcnt[w];
            base += (w < wave) ? v : 0;
            cnt  += v;
        }
        if (spike) {
            int pos = base + __popcll(mask & ((1ull << lane) - 1ull));
            list[pos] = tid;
        }
        __syncthreads();                    // list complete

        // ---- fc1: counted sparse loop, 4 independent f64 partials ----
        double s0 = 0.0, s1 = 0.0, s2 = 0.0, s3 = 0.0;
        const float* fw = fc1wT + tid;
        int i = 0;
        for (; i + 4 <= cnt; i += 4) {
            int cA = list[i], cB = list[i + 1], cC = list[i + 2], cD = list[i + 3];
            float wA = fw[(size_t)cA * COUT];
            float wB = fw[(size_t)cB * COUT];
            float wC = fw[(size_t)cC * COUT];
            float wD = fw[(size_t)cD * COUT];
            s0 += (double)wA;
            s1 += (double)wB;
            s2 += (double)wC;
            s3 += (double)wD;
        }
        for (; i < cnt; ++i) s0 += (double)fw[(size_t)list[i] * COUT];
        double cur1 = ((s0 + s1) + (s2 + s3)) + f1b;

        // ---- hidden leaky + fc2 partials ----
        double h = bh * hm + cur1 - ((hm > 1.0) ? 1.0 : 0.0);
        hm = h;
        double sh = (h > 1.0) ? 1.0 : 0.0;
        double p0 = sh * w2a;
        double p1 = sh * w2b;
        #pragma unroll
        for (int off = 32; off > 0; off >>= 1) {
            p0 += __shfl_down(p0, off);
            p1 += __shfl_down(p1, off);
        }
        if (lane == 0) { red[wave][0] = p0; red[wave][1] = p1; }
        __syncthreads();                    // red ready; list reads done

        // ---- output layer (threads 0/1 = class j) ----
        if (tid < 2) {
            double cur2 = f2b;
            #pragma unroll
            for (int w = 0; w < 8; ++w) cur2 += red[w][tid];
            double o = bo * om + cur2 - ((om > 1.0) ? 1.0 : 0.0);
            om = o;
            float so = (o > 1.0) ? 1.0f : 0.0f;
            int bidx = brow * 2 + tid;
            out[2048 + t * 2048 + bidx] = so;               // spk_rec
            out[2048 + 63488 + t * 2048 + bidx] = (float)o; // mem_rec
            if (t == T_STEPS - 1) out[bidx] = (float)o;     // final om
        }
    }
}

// ---------------------------------------------------------------------------
extern "C" void kernel_launch(void* const* d_in, const int* in_sizes, int n_in,
                              void* d_out, int out_size, void* d_ws, size_t ws_size,
                              hipStream_t stream)
{
    const float* x        = (const float*)d_in[0];
    const float* conv_w   = (const float*)d_in[1];
    const float* conv_b   = (const float*)d_in[2];
    const float* bn_gamma = (const float*)d_in[3];
    const float* bn_beta  = (const float*)d_in[4];
    const float* bn_mean  = (const float*)d_in[5];
    const float* bn_var   = (const float*)d_in[6];
    const float* fc1_w    = (const float*)d_in[7];
    const float* fc1_b    = (const float*)d_in[8];
    const float* fc2_w    = (const float*)d_in[9];
    const float* fc2_b    = (const float*)d_in[10];
    const float* beta_enc = (const float*)d_in[11];
    const float* beta_hid = (const float*)d_in[12];
    const float* beta_out = (const float*)d_in[13];
    float* out = (float*)d_out;

    float*  wT    = (float*)d_ws;                       // [2048][512] f32, 4 MB
    float*  fc1wT = wT + (size_t)KRED * COUT;           // [512][512]  f32, 1 MB
    double* seq   = (double*)(fc1wT + (size_t)COUT * COUT); // [15872][512] f64, 65 MB

    prep_kernel<<<4096, 256, 0, stream>>>(conv_w, fc1_w, wT, fc1wT);

    for (int chunk = 0; chunk < 2; ++chunk) {
        int b_base = chunk * BCHUNK;
        conv_bn_f64_kernel<<<(MCHUNK / 64) * (COUT / 64), 256, 0, stream>>>(
            x, wT, conv_b, bn_gamma, bn_beta, bn_mean, bn_var, seq, b_base);
        snn_scan_v3_kernel<<<BCHUNK, 512, 0, stream>>>(
            seq, fc1wT, fc1_b, fc2_w, fc2_b, beta_enc, beta_hid, beta_out, out, b_base);
    }
}